// Round 7
// baseline (457.616 us; speedup 1.0000x reference)
//
#include <hip/hip_runtime.h>
#include <hip/hip_bf16.h>

#define DEVFN static __device__ __forceinline__

typedef __attribute__((ext_vector_type(8))) __bf16 bf16x8;
typedef __attribute__((ext_vector_type(4))) float f32x4;

#define MFMA16(a, b, c) __builtin_amdgcn_mfma_f32_16x16x32_bf16(a, b, c, 0, 0, 0)

// async global->LDS, 16B per lane; dest is wave-uniform base + lane*16
DEVFN void gload16(const void* g, void* l) {
  __builtin_amdgcn_global_load_lds((const __attribute__((address_space(1))) void*)g,
                                   (__attribute__((address_space(3))) void*)l, 16, 0, 0);
}

DEVFN void vwait8() { asm volatile("s_waitcnt vmcnt(8)" ::: "memory"); __builtin_amdgcn_sched_barrier(0); }
DEVFN void vwait4() { asm volatile("s_waitcnt vmcnt(4)" ::: "memory"); __builtin_amdgcn_sched_barrier(0); }
DEVFN void vwait0() { asm volatile("s_waitcnt vmcnt(0)" ::: "memory"); __builtin_amdgcn_sched_barrier(0); }
DEVFN void bar()    { __builtin_amdgcn_s_barrier(); }
// barrier + scheduling fence: nothing may hoist above this point
DEVFN void barsched() { __builtin_amdgcn_s_barrier(); __builtin_amdgcn_sched_barrier(0); }

// ---------------- f32 -> bf16 convert (vectorized) ----------------
__global__ __launch_bounds__(256) void cvt_f32_bf16(const float* __restrict__ in,
                                                    __bf16* __restrict__ out) {
  size_t i = ((size_t)blockIdx.x * 256 + threadIdx.x) * 8;
  f32x4 a = *(const f32x4*)(in + i);
  f32x4 b = *(const f32x4*)(in + i + 4);
  bf16x8 u;
  u[0] = (__bf16)a[0]; u[1] = (__bf16)a[1]; u[2] = (__bf16)a[2]; u[3] = (__bf16)a[3];
  u[4] = (__bf16)b[0]; u[5] = (__bf16)b[1]; u[6] = (__bf16)b[2]; u[7] = (__bf16)b[3];
  *(bf16x8*)(out + i) = u;
}

// ---------------- transpose f32 [K][N] -> bf16 [N][K] ----------------
__global__ __launch_bounds__(256) void transpose_w(const float* __restrict__ in,
                                                   __bf16* __restrict__ out,
                                                   int K, int N) {
  __shared__ float tile[32][33];
  const int t = threadIdx.x, tx = t & 31, ty = t >> 5;
  const int n0 = blockIdx.x * 32, k0 = blockIdx.y * 32;
#pragma unroll
  for (int r = 0; r < 4; r++)
    tile[ty + r * 8][tx] = in[(size_t)(k0 + ty + r * 8) * N + n0 + tx];
  __syncthreads();
#pragma unroll
  for (int r = 0; r < 4; r++)
    out[(size_t)(n0 + ty + r * 8) * K + k0 + tx] = (__bf16)tile[tx][ty + r * 8];
}

// ---------------- transpose bf16 [bh][T][128] -> [bh][128][T] ----------------
__global__ __launch_bounds__(256) void transpose_v(const __bf16* __restrict__ in,
                                                   __bf16* __restrict__ out) {
  __shared__ __bf16 tile[64][72];
  const int bh = blockIdx.z;
  const int t0 = blockIdx.x * 64, d0 = blockIdx.y * 64;
  const int tid = threadIdx.x;
  const int r = tid >> 3, c8 = (tid & 7) * 8;
  const __bf16* ip = in + (size_t)bh * 2048 * 128;
#pragma unroll
  for (int i = 0; i < 2; i++)
    *(bf16x8*)&tile[i * 32 + r][c8] =
        *(const bf16x8*)(ip + (size_t)(t0 + i * 32 + r) * 128 + d0 + c8);
  __syncthreads();
  __bf16* op = out + (size_t)bh * 2048 * 128;
#pragma unroll
  for (int i = 0; i < 2; i++) {
    const int dd = i * 32 + r;
    bf16x8 v;
#pragma unroll
    for (int j = 0; j < 8; j++) v[j] = tile[c8 + j][dd];
    *(bf16x8*)(op + (size_t)(d0 + dd) * 2048 + t0 + c8) = v;
  }
}

// ================= 256x256 8-phase bf16 GEMM (m201 template) =================
#define QK_SCALE 0.12751745f  // (1/sqrt(128)) * log2(e)

DEVFN void stage_tile(const __bf16* gx, size_t Kst, int t, __bf16* ldst,
                      int rr, int gsw, int w) {
#pragma unroll
  for (int j = 0; j < 4; j++)
    gload16(gx + (size_t)(j * 64 + rr) * Kst + (size_t)t * 64 + gsw,
            ldst + j * 4096 + w * 512);
}

DEVFN void stage_chunk(const __bf16* gx, size_t Kst, int t, __bf16* ldst, int j,
                       int rr, int gsw, int w) {
  gload16(gx + (size_t)(j * 64 + rr) * Kst + (size_t)t * 64 + gsw,
          ldst + j * 4096 + w * 512);
}

// Per K-tile: 4 phases x 16 MFMA. Stage of tile t+2 spread per-phase (m196):
//   after ph1: A chunks {0,2} (rows 0-63,128-191 consumed in ph1)
//   after ph2: B chunks {0,1} (B fully consumed)
//   after ph3: B chunks {2,3} + A chunks {1,3} (A fully consumed)
DEVFN void tile_step(__bf16* la, __bf16* lb, f32x4 (&acc)[8][4],
                     const __bf16* ga, const __bf16* gb, size_t Kst, int t, int NT,
                     int rr, int gsw, int w, int wr, int wc, int lg, int li) {
  bf16x8 a[4][2], bl[2][2], br[2][2];
  const int sa = li & 7;
  const int arow = wr * 128 + li;
  const int brow = wc * 64 + li;
  const bool pf = (t + 2 < NT);

  // ---- phase 1: read A(mi0-3) + B(ni0-1); MFMA (mi0-3 x ni0-1)
#pragma unroll
  for (int mi = 0; mi < 4; mi++)
#pragma unroll
    for (int ks = 0; ks < 2; ks++)
      a[mi][ks] = *(const bf16x8*)&la[(arow + mi * 16) * 64 + (((ks * 4 + lg) ^ sa) * 8)];
#pragma unroll
  for (int ni = 0; ni < 2; ni++)
#pragma unroll
    for (int ks = 0; ks < 2; ks++)
      bl[ni][ks] = *(const bf16x8*)&lb[(brow + ni * 16) * 64 + (((ks * 4 + lg) ^ sa) * 8)];
  bar();
  __builtin_amdgcn_s_setprio(1);
#pragma unroll
  for (int mi = 0; mi < 4; mi++)
#pragma unroll
    for (int ni = 0; ni < 2; ni++)
#pragma unroll
      for (int ks = 0; ks < 2; ks++)
        acc[mi][ni] = MFMA16(a[mi][ks], bl[ni][ks], acc[mi][ni]);
  __builtin_amdgcn_s_setprio(0);
  barsched();   // ph1 close: A chunks {0,2} of this buffer are free

  // ---- phase 2: read B(ni2-3); stage A{0,2}; MFMA (mi0-3 x ni2-3)
#pragma unroll
  for (int ni = 0; ni < 2; ni++)
#pragma unroll
    for (int ks = 0; ks < 2; ks++)
      br[ni][ks] = *(const bf16x8*)&lb[(brow + (ni + 2) * 16) * 64 + (((ks * 4 + lg) ^ sa) * 8)];
  if (pf) {
    stage_chunk(ga, Kst, t + 2, la, 0, rr, gsw, w);
    stage_chunk(ga, Kst, t + 2, la, 2, rr, gsw, w);
  }
  bar();
  __builtin_amdgcn_s_setprio(1);
#pragma unroll
  for (int mi = 0; mi < 4; mi++)
#pragma unroll
    for (int ni = 0; ni < 2; ni++)
#pragma unroll
      for (int ks = 0; ks < 2; ks++)
        acc[mi][ni + 2] = MFMA16(a[mi][ks], br[ni][ks], acc[mi][ni + 2]);
  __builtin_amdgcn_s_setprio(0);
  barsched();   // ph2 close: B fully read by all waves

  // ---- phase 3: read A(mi4-7); stage B{0,1}; MFMA (mi4-7 x ni0-1)
#pragma unroll
  for (int mi = 0; mi < 4; mi++)
#pragma unroll
    for (int ks = 0; ks < 2; ks++)
      a[mi][ks] = *(const bf16x8*)&la[(arow + (mi + 4) * 16) * 64 + (((ks * 4 + lg) ^ sa) * 8)];
  if (pf) {
    stage_chunk(gb, Kst, t + 2, lb, 0, rr, gsw, w);
    stage_chunk(gb, Kst, t + 2, lb, 1, rr, gsw, w);
  }
  bar();
  __builtin_amdgcn_s_setprio(1);
#pragma unroll
  for (int mi = 0; mi < 4; mi++)
#pragma unroll
    for (int ni = 0; ni < 2; ni++)
#pragma unroll
      for (int ks = 0; ks < 2; ks++)
        acc[mi + 4][ni] = MFMA16(a[mi][ks], bl[ni][ks], acc[mi + 4][ni]);
  __builtin_amdgcn_s_setprio(0);
  barsched();   // ph3 close: A fully read by all waves

  // ---- phase 4: stage B{2,3} + A{1,3}; MFMA (mi4-7 x ni2-3)
  if (pf) {
    stage_chunk(gb, Kst, t + 2, lb, 2, rr, gsw, w);
    stage_chunk(gb, Kst, t + 2, lb, 3, rr, gsw, w);
    stage_chunk(ga, Kst, t + 2, la, 1, rr, gsw, w);
    stage_chunk(ga, Kst, t + 2, la, 3, rr, gsw, w);
  }
  __builtin_amdgcn_s_setprio(1);
#pragma unroll
  for (int mi = 0; mi < 4; mi++)
#pragma unroll
    for (int ni = 0; ni < 2; ni++)
#pragma unroll
      for (int ks = 0; ks < 2; ks++)
        acc[mi + 4][ni + 2] = MFMA16(a[mi][ks], br[ni][ks], acc[mi + 4][ni + 2]);
  __builtin_amdgcn_s_setprio(0);

  // retire tile t+1's loads; leave t+2's 8 in flight (counted vmcnt, T4)
  if (pf) vwait8(); else vwait0();
  bar();
}

template <int MODE>
__global__ __launch_bounds__(512, 2) void gemm256(
    const __bf16* __restrict__ A, const __bf16* __restrict__ Bt,
    const float* __restrict__ bias, int K, int Ncols,
    __bf16* __restrict__ qo, __bf16* __restrict__ ko, __bf16* __restrict__ vo,
    float* __restrict__ outf) {
  __shared__ __align__(16) __bf16 lds[65536];
  const int tid = threadIdx.x;
  const int w = tid >> 6, lane = tid & 63;
  const int wr = w >> 2, wc = w & 3;
  const int lg = lane >> 4, li = lane & 15;
  // 2D-chunked XCD map (T1): XCD x <- (xr,xc); region (nbx/2) cols x 8 rows,
  // traversed m-major in n-bands of 4. Requires nby == 32 (both launches).
  const int nbx = gridDim.x;
  const int orig = (int)blockIdx.y * nbx + (int)blockIdx.x;
  const int x = orig & 7, i = orig >> 3;
  const int xc = x & 1, xr = x >> 1;
  const int hw = nbx >> 1;
  const int band = i >> 5;
  const int j = i & 31;
  const size_t n0 = (size_t)(xc * hw + band * 4 + (j & 3)) * 256;
  const size_t m0 = (size_t)(xr * 8 + (j >> 2)) * 256;
  const int rr = tid >> 3;
  const int gsw = ((tid & 7) ^ (rr & 7)) * 8;
  const __bf16* ga = A + m0 * K;
  const __bf16* gb = Bt + n0 * K;
  const int NT = K >> 6;

  __bf16* la0 = lds;
  __bf16* la1 = lds + 16384;
  __bf16* lb0 = lds + 32768;
  __bf16* lb1 = lds + 49152;

  f32x4 acc[8][4] = {};

  stage_tile(ga, K, 0, la0, rr, gsw, w);
  stage_tile(gb, K, 0, lb0, rr, gsw, w);
  stage_tile(ga, K, 1, la1, rr, gsw, w);
  stage_tile(gb, K, 1, lb1, rr, gsw, w);
  vwait8();
  bar();

  for (int t = 0; t < NT; t += 2) {
    tile_step(la0, lb0, acc, ga, gb, K, t,     NT, rr, gsw, w, wr, wc, lg, li);
    tile_step(la1, lb1, acc, ga, gb, K, t + 1, NT, rr, gsw, w, wr, wc, lg, li);
  }

  if (MODE == 0) {
    const int which = (int)(n0 >> 11);
    const int b = (int)(m0 >> 11);
    __bf16* outp = (which == 0) ? qo : ((which == 1) ? ko : vo);
    const float scale = (which == 0) ? QK_SCALE : 1.0f;
#pragma unroll
    for (int ni = 0; ni < 4; ni++) {
      const int ncol = (int)n0 + wc * 64 + ni * 16 + li;
      const float bv = bias[ncol];
      const int h = (ncol & 2047) >> 7;
      const int d = ncol & 127;
      const size_t base = (size_t)(b * 16 + h) * (2048 * 128) + d;
#pragma unroll
      for (int mi = 0; mi < 8; mi++)
#pragma unroll
        for (int r = 0; r < 4; r++) {
          const int tt = ((int)m0 + wr * 128 + mi * 16 + lg * 4 + r) & 2047;
          outp[base + (size_t)tt * 128] = (__bf16)((acc[mi][ni][r] + bv) * scale);
        }
    }
  } else {
#pragma unroll
    for (int ni = 0; ni < 4; ni++) {
      const int ncol = (int)n0 + wc * 64 + ni * 16 + li;
      const float bv = bias[ncol];
#pragma unroll
      for (int mi = 0; mi < 8; mi++)
#pragma unroll
        for (int r = 0; r < 4; r++) {
          const size_t mrow = m0 + wr * 128 + mi * 16 + lg * 4 + r;
          outf[mrow * Ncols + ncol] = acc[mi][ni][r] + bv;
        }
    }
  }
}

// ---------------- causal flash attention, pipelined staging ----------------
DEVFN void attn_stageK(const __bf16* const (&ksrc)[4], int k0, __bf16* Kl, int w) {
#pragma unroll
  for (int i = 0; i < 4; i++)
    gload16(ksrc[i] + (size_t)k0 * 128, Kl + i * 2048 + w * 512);
}
DEVFN void attn_stageV(const __bf16* const (&vsrc)[4], int k0, __bf16* Vl, int w) {
#pragma unroll
  for (int i = 0; i < 4; i++)
    gload16(vsrc[i] + k0, Vl + i * 2048 + w * 512);
}

template <bool DIAG>
DEVFN void attn_tile(int kt, int n, int q0, int w, int lg, int li,
                     const __bf16* const (&ksrc)[4], const __bf16* const (&vsrc)[4],
                     __bf16* Kl, __bf16* Vl, __bf16* Pl,
                     const bf16x8 (&qf)[2][4], f32x4 (&o)[2][8],
                     float (&mrow)[2][4], float (&lrow)[2][4]) {
  const int k0 = kt * 64;
  const bool more = (kt + 1 < n);

  vwait4();      // K(kt) landed (V(kt) still in flight)
  barsched();

  // S = Q K^T
  f32x4 s[2][4] = {};
#pragma unroll
  for (int kk = 0; kk < 4; kk++) {
    bf16x8 bk[4];
#pragma unroll
    for (int ni = 0; ni < 4; ni++) {
      const int key = ni * 16 + li;
      bk[ni] = *(const bf16x8*)&Kl[key * 128 + ((kk * 32 + lg * 8) ^ ((key & 7) << 3))];
    }
#pragma unroll
    for (int mi = 0; mi < 2; mi++)
#pragma unroll
      for (int ni = 0; ni < 4; ni++)
        s[mi][ni] = MFMA16(qf[mi][kk], bk[ni], s[mi][ni]);
  }
  barsched();    // all waves done reading Kl
  if (more) attn_stageK(ksrc, k0 + 64, Kl, w);

  // online softmax (base-2) with defer-max
#pragma unroll
  for (int mi = 0; mi < 2; mi++) {
#pragma unroll
    for (int r = 0; r < 4; r++) {
      const int prow = w * 32 + mi * 16 + lg * 4 + r;
      float vals[4];
#pragma unroll
      for (int ni = 0; ni < 4; ni++) {
        float x = s[mi][ni][r];
        if (DIAG) {
          if ((k0 + ni * 16 + li) > (q0 + prow)) x = -1e30f;
        }
        vals[ni] = x;
      }
      float vmax = fmaxf(fmaxf(vals[0], vals[1]), fmaxf(vals[2], vals[3]));
      vmax = fmaxf(vmax, __shfl_xor(vmax, 1));
      vmax = fmaxf(vmax, __shfl_xor(vmax, 2));
      vmax = fmaxf(vmax, __shfl_xor(vmax, 4));
      vmax = fmaxf(vmax, __shfl_xor(vmax, 8));
      float mref = mrow[mi][r];
      if (vmax - mref > 8.0f) {
        const float sc = __builtin_amdgcn_exp2f(mref - vmax);
        lrow[mi][r] *= sc;
#pragma unroll
        for (int nd = 0; nd < 8; nd++) o[mi][nd][r] *= sc;
        mrow[mi][r] = vmax;
        mref = vmax;
      }
      float ps = 0.f;
#pragma unroll
      for (int ni = 0; ni < 4; ni++) {
        const float p = __builtin_amdgcn_exp2f(vals[ni] - mref);
        ps += p;
        Pl[prow * 72 + ni * 16 + li] = (__bf16)p;
      }
      ps += __shfl_xor(ps, 1);
      ps += __shfl_xor(ps, 2);
      ps += __shfl_xor(ps, 4);
      ps += __shfl_xor(ps, 8);
      lrow[mi][r] += ps;
    }
  }

  if (more) vwait4(); else vwait0();   // V(kt) landed (K(kt+1) may remain)
  barsched();

  // O += P V
#pragma unroll
  for (int kk = 0; kk < 2; kk++) {
    bf16x8 pf[2];
#pragma unroll
    for (int mi = 0; mi < 2; mi++)
      pf[mi] = *(const bf16x8*)&Pl[(w * 32 + mi * 16 + li) * 72 + kk * 32 + lg * 8];
#pragma unroll
    for (int nd = 0; nd < 8; nd++) {
      const int d = nd * 16 + li;
      const int swd = ((d ^ (d >> 3)) & 7) << 3;
      bf16x8 vf = *(const bf16x8*)&Vl[d * 64 + ((kk * 32 + lg * 8) ^ swd)];
#pragma unroll
      for (int mi = 0; mi < 2; mi++)
        o[mi][nd] = MFMA16(pf[mi], vf, o[mi][nd]);
    }
  }
  barsched();    // all waves done reading Vl
  if (more) attn_stageV(vsrc, k0 + 64, Vl, w);
}

DEVFN void attn_run(int qt, int bh, int w, int lg, int li,
                    const __bf16* qp, __bf16* ob,
                    const __bf16* const (&ksrc)[4], const __bf16* const (&vsrc)[4],
                    __bf16* Kl, __bf16* Vl, __bf16* Pl) {
  const int q0 = qt * 128;
  bf16x8 qf[2][4];
#pragma unroll
  for (int mi = 0; mi < 2; mi++)
#pragma unroll
    for (int kk = 0; kk < 4; kk++)
      qf[mi][kk] = *(const bf16x8*)(qp + (size_t)(q0 + w * 32 + mi * 16 + li) * 128 + kk * 32 + lg * 8);

  f32x4 o[2][8] = {};
  float mrow[2][4], lrow[2][4];
#pragma unroll
  for (int mi = 0; mi < 2; mi++)
#pragma unroll
    for (int r = 0; r < 4; r++) { mrow[mi][r] = -1e30f; lrow[mi][r] = 0.f; }

  const int n = 2 * qt + 2;
  attn_stageK(ksrc, 0, Kl, w);
  attn_stageV(vsrc, 0, Vl, w);

  for (int kt = 0; kt < n - 2; kt++)
    attn_tile<false>(kt, n, q0, w, lg, li, ksrc, vsrc, Kl, Vl, Pl, qf, o, mrow, lrow);
  attn_tile<true>(n - 2, n, q0, w, lg, li, ksrc, vsrc, Kl, Vl, Pl, qf, o, mrow, lrow);
  attn_tile<true>(n - 1, n, q0, w, lg, li, ksrc, vsrc, Kl, Vl, Pl, qf, o, mrow, lrow);

  const int b = bh >> 4, h = bh & 15;
#pragma unroll
  for (int mi = 0; mi < 2; mi++) {
    float inv[4];
#pragma unroll
    for (int r = 0; r < 4; r++) inv[r] = 1.0f / lrow[mi][r];
#pragma unroll
    for (int nd = 0; nd < 8; nd++)
#pragma unroll
      for (int r = 0; r < 4; r++)
        ob[(size_t)(b * 2048 + q0 + w * 32 + mi * 16 + lg * 4 + r) * 2048 + h * 128 + nd * 16 + li]
            = (__bf16)(o[mi][nd][r] * inv[r]);
  }
}

__global__ __launch_bounds__(256, 2) void attn_fwd(
    const __bf16* __restrict__ qb, const __bf16* __restrict__ kb,
    const __bf16* __restrict__ vtb, __bf16* __restrict__ ob) {
  __shared__ __align__(16) __bf16 Kl[64 * 128];
  __shared__ __align__(16) __bf16 Vl[128 * 64];
  __shared__ __align__(16) __bf16 Pl[128 * 72];
  // XCD swizzle: all 8 q-blocks of a bh land on one XCD (K/V L2 locality)
  const int orig = (int)blockIdx.y * 8 + (int)blockIdx.x;
  const int swz = (orig & 7) * 64 + (orig >> 3);
  const int bx = swz & 7;
  const int bh = swz >> 3;
  const int tid = threadIdx.x;
  const int w = tid >> 6, l = tid & 63;
  const int lg = l >> 4, li = l & 15;
  const __bf16* qp = qb + (size_t)bh * (2048 * 128);
  const __bf16* kp = kb + (size_t)bh * (2048 * 128);
  const __bf16* vtp = vtb + (size_t)bh * (2048 * 128);

  const __bf16* ksrc[4];
  const __bf16* vsrc[4];
#pragma unroll
  for (int i = 0; i < 4; i++) {
    const int key = i * 16 + w * 4 + lg;
    ksrc[i] = kp + (size_t)key * 128 + 8 * (li ^ (key & 7));
    const int d = i * 32 + (tid >> 3);
    const int g = (tid & 7) ^ ((d ^ (d >> 3)) & 7);
    vsrc[i] = vtp + (size_t)d * 2048 + g * 8;
  }

  // large q-tile first, then the small one: 34 tiles total per block
  attn_run(15 - bx, bh, w, lg, li, qp, ob, ksrc, vsrc, Kl, Vl, Pl);
  attn_run(bx,      bh, w, lg, li, qp, ob, ksrc, vsrc, Kl, Vl, Pl);
}

extern "C" void kernel_launch(void* const* d_in, const int* in_sizes, int n_in,
                              void* d_out, int out_size, void* d_ws, size_t ws_size,
                              hipStream_t stream) {
  (void)in_sizes; (void)n_in; (void)out_size; (void)ws_size;
  const float* x     = (const float*)d_in[0];
  const float* w_qkv = (const float*)d_in[1];
  const float* b_qkv = (const float*)d_in[2];
  const float* w_out = (const float*)d_in[3];
  const float* b_out = (const float*)d_in[4];
  float* out = (float*)d_out;
  char* ws = (char*)d_ws;

  __bf16* xb    = (__bf16*)(ws + 0);           // x-bf16, later V^T
  __bf16* wqkvT = (__bf16*)(ws + 33554432);    // w_qkv^T bf16 [6144][2048]
  __bf16* qbuf  = (__bf16*)(ws + 58720256);    // [B*H][T][hd]
  __bf16* kbuf  = (__bf16*)(ws + 92274688);
  __bf16* vbuf  = (__bf16*)(ws + 125829120);   // V, later attn out
  __bf16* woutT = (__bf16*)(ws + 159383552);   // w_out^T bf16 [2048][2048]

  cvt_f32_bf16<<<8192, 256, 0, stream>>>(x, xb);
  transpose_w<<<dim3(192, 64), 256, 0, stream>>>(w_qkv, wqkvT, 2048, 6144);
  transpose_w<<<dim3(64, 64), 256, 0, stream>>>(w_out, woutT, 2048, 2048);
  gemm256<0><<<dim3(24, 32), 512, 0, stream>>>(xb, wqkvT, b_qkv, 2048, 6144,
                                               qbuf, kbuf, vbuf, nullptr);
  transpose_v<<<dim3(32, 2, 64), 256, 0, stream>>>(vbuf, xb);   // xb := V^T
  attn_fwd<<<dim3(8, 64), 256, 0, stream>>>(qbuf, kbuf, xb, vbuf);  // vbuf := attn out
  gemm256<1><<<dim3(8, 32), 512, 0, stream>>>(vbuf, woutT, b_out, 2048, 2048,
                                              nullptr, nullptr, nullptr, out);
}